// Round 6
// baseline (114.482 us; speedup 1.0000x reference)
//
#include <hip/hip_runtime.h>
#include <hip/hip_bf16.h>

typedef __attribute__((ext_vector_type(8))) short bf16x8;
typedef __attribute__((ext_vector_type(4))) float f32x4;
typedef __attribute__((ext_vector_type(16))) float f32x16;

static __device__ __forceinline__ unsigned short f2bf(float f) {
  union { float f; unsigned int u; } v; v.f = f;
  unsigned int u = v.u;
  return (unsigned short)((u + 0x7FFFu + ((u >> 16) & 1u)) >> 16);
}

__device__ __forceinline__ void async_ld16(const void* g, void* l) {
  __builtin_amdgcn_global_load_lds(
      (const __attribute__((address_space(1))) unsigned int*)g,
      (__attribute__((address_space(3))) unsigned int*)l, 16, 0, 0);
}

// fp32 -> bf16 for x + W_K/W_Q/W_V/W_O; W_Q gets 0.125*log2(e) folded in
__global__ __launch_bounds__(256) void cvt_all(
    const float* __restrict__ x, const float* __restrict__ wk,
    const float* __restrict__ wq, const float* __restrict__ wv,
    const float* __restrict__ wo, unsigned short* __restrict__ dst) {
  int i = blockIdx.x * 256 + threadIdx.x;
  int e0 = i * 4;
  const float* src;
  int off;
  float scale = 1.0f;
  if (e0 < 3145728) { src = x; off = e0; }
  else {
    int j = e0 - 3145728;
    int a = j / 589824;
    off = j - a * 589824;
    src = (a == 0) ? wk : (a == 1) ? wq : (a == 2) ? wv : wo;
    if (a == 1) scale = 0.18033688011112042f;  // 0.125 * log2(e)
  }
  float4 v = *(const float4*)(src + off);
  ushort4 r;
  r.x = f2bf(v.x * scale); r.y = f2bf(v.y * scale);
  r.z = f2bf(v.z * scale); r.w = f2bf(v.w * scale);
  *(ushort4*)(dst + e0) = r;
}

// single-buffered 128x128 tile GEMM (m97 structure), K=768.
// MODE 0: fused QKV epilogue (N=2304 -> kb/qb [B,H,P,64], v4 tiled)
// MODE 1: fp32 linear out (N=768)
template <int MODE>
__device__ __forceinline__ void gemm_body(
    const unsigned short* __restrict__ A,
    const unsigned short* __restrict__ Bt,
    void* __restrict__ outK, void* __restrict__ outQ, void* __restrict__ outV,
    unsigned short* As, unsigned short* Bs) {
  const int tid = threadIdx.x;
  const int w = tid >> 6;
  const int l = tid & 63;
  const int g = l >> 4;
  const int c = l & 15;
  const int m0 = blockIdx.y * 128;
  const int n0 = blockIdx.x * 128;
  const int wr = w >> 1, wc = w & 1;

  f32x4 acc[4][4];
#pragma unroll
  for (int i = 0; i < 4; i++)
#pragma unroll
    for (int j = 0; j < 4; j++) acc[i][j] = (f32x4){0.f, 0.f, 0.f, 0.f};

  const int lrow = l >> 3;
  const int lcolx = ((l & 7) ^ lrow) * 8;

  for (int kt = 0; kt < 12; ++kt) {
    const int k0 = kt * 64;
#pragma unroll
    for (int cc = 0; cc < 4; ++cc) {
      int chunk = cc * 4 + w;
      int row = chunk * 8 + lrow;
      async_ld16(A + (m0 + row) * 768 + k0 + lcolx, &As[chunk * 512]);
      async_ld16(Bt + (n0 + row) * 768 + k0 + lcolx, &Bs[chunk * 512]);
    }
    __syncthreads();
#pragma unroll
    for (int ks = 0; ks < 2; ++ks) {
      bf16x8 a[4], b[4];
#pragma unroll
      for (int mi = 0; mi < 4; ++mi) {
        int row = wr * 64 + mi * 16 + c;
        int col = (ks * 32 + g * 8) ^ ((row & 7) * 8);
        a[mi] = *(const bf16x8*)&As[row * 64 + col];
      }
#pragma unroll
      for (int ni = 0; ni < 4; ++ni) {
        int row = wc * 64 + ni * 16 + c;
        int col = (ks * 32 + g * 8) ^ ((row & 7) * 8);
        b[ni] = *(const bf16x8*)&Bs[row * 64 + col];
      }
#pragma unroll
      for (int mi = 0; mi < 4; ++mi)
#pragma unroll
        for (int ni = 0; ni < 4; ++ni)
          acc[mi][ni] = __builtin_amdgcn_mfma_f32_16x16x32_bf16(a[mi], b[ni], acc[mi][ni], 0, 0, 0);
    }
    __syncthreads();
  }

  if (MODE == 1) {
    float* O = (float*)outK;
#pragma unroll
    for (int mi = 0; mi < 4; ++mi)
#pragma unroll
      for (int ni = 0; ni < 4; ++ni)
#pragma unroll
        for (int r = 0; r < 4; ++r) {
          int m = m0 + wr * 64 + mi * 16 + g * 4 + r;
          int n = n0 + wc * 64 + ni * 16 + c;
          O[(long)m * 768 + n] = acc[mi][ni][r];
        }
  } else {
    const int which = (n0 >= 1536) ? 2 : (n0 >= 768 ? 1 : 0);
    const int nb = n0 - which * 768;
    unsigned short* O01 = (unsigned short*)(which == 1 ? outQ : outK);
    unsigned short* OV = (unsigned short*)outV;
#pragma unroll
    for (int mi = 0; mi < 4; ++mi)
#pragma unroll
      for (int ni = 0; ni < 4; ++ni)
#pragma unroll
        for (int r = 0; r < 4; ++r) {
          int m = m0 + wr * 64 + mi * 16 + g * 4 + r;
          int nn = nb + wc * 64 + ni * 16 + c;
          int b = m >> 11, p = m & 2047;
          int h = nn >> 6, e = nn & 63;
          unsigned short val = f2bf(acc[mi][ni][r]);
          if (which == 2) {
            long idx = (long)(b * 12 + h) * 131072 + (p >> 4) * 1024 + e * 16 + (p & 15);
            OV[idx] = val;
          } else {
            O01[(((long)(b * 12 + h) * 2048 + p) << 6) + e] = val;
          }
        }
  }
}

__global__ __launch_bounds__(256) void gemm_qkv(
    const unsigned short* __restrict__ A,
    const unsigned short* __restrict__ Wkqv,   // [2304][768] = [Wk;Wq;Wv]
    unsigned short* __restrict__ kb, unsigned short* __restrict__ qb,
    unsigned short* __restrict__ v4b) {
  __shared__ __align__(16) unsigned short As[8192];
  __shared__ __align__(16) unsigned short Bs[8192];
  gemm_body<0>(A, Wkqv, kb, qb, v4b, As, Bs);
}

__global__ __launch_bounds__(256) void gemm_out(
    const unsigned short* __restrict__ A,
    const unsigned short* __restrict__ Bt,
    float* __restrict__ out) {
  __shared__ __align__(16) unsigned short As[8192];
  __shared__ __align__(16) unsigned short Bs[8192];
  gemm_body<1>(A, Bt, out, nullptr, nullptr, As, Bs);
}

// causal flash attention: 4 waves/block, wave w owns q-chunk 4*qb+w (32 rows);
// K/V tiles (64 k-rows) staged cooperatively into double-buffered LDS;
// swapped QK^T (32x32x16), in-register softmax, counted-vmcnt pipeline.
__global__ __launch_bounds__(256) void attn(
    const unsigned short* __restrict__ Q,
    const unsigned short* __restrict__ K,
    const unsigned short* __restrict__ V4,
    unsigned short* __restrict__ Z) {
  __shared__ __align__(16) unsigned short Ks[2][4096];
  __shared__ __align__(16) unsigned short Vs[2][4096];
  const int bx = blockIdx.x;                 // 0..383
  const int qidx = bx / 24;
  const int bh = bx - qidx * 24;             // fast-varying -> 3 bh per XCD
  const int qb = 15 - qidx;                  // LPT: heavy q-blocks first
  const int tid = threadIdx.x;
  const int w = tid >> 6;
  const int l = tid & 63;
  const int ql = l & 31;
  const int hi = l >> 5;
  const int c = qb * 4 + w;                  // wave's q-chunk (32 rows)
  const int b = bh / 12, hd = bh - b * 12;
  const long base = (long)bh * 2048 * 64;
  const long vbase = (long)bh * 131072;
  const int q0 = c * 32;
  const int lrow = l >> 3;
  const int lcolx = ((l & 7) ^ lrow) * 8;
  const int ktmax = 2 * qb + 1;              // inclusive last K-tile

  // Q B-fragments (col = lane&31 = q-row, elems = d)
  bf16x8 qf[4];
  {
    const unsigned short* qp = Q + base + (long)(q0 + ql) * 64 + hi * 8;
#pragma unroll
    for (int d = 0; d < 4; ++d) qf[d] = *(const bf16x8*)(qp + d * 16);
  }

  f32x16 o0, o1;
#pragma unroll
  for (int r = 0; r < 16; ++r) { o0[r] = 0.f; o1[r] = 0.f; }
  float lsum = 0.f;

  auto stage = [&](int buf, int kt) {
#pragma unroll
    for (int cc = 0; cc < 2; ++cc) {
      int chunk = w * 2 + cc;
      int row = chunk * 8 + lrow;
      async_ld16(K + base + (long)(kt * 64 + row) * 64 + lcolx, &Ks[buf][chunk * 512]);
    }
#pragma unroll
    for (int cc = 0; cc < 2; ++cc) {
      int chunk = w * 2 + cc;
      async_ld16(V4 + vbase + kt * 4096 + chunk * 512 + l * 8, &Vs[buf][chunk * 512]);
    }
  };

  auto subtile = [&](int cur, int sl, int sg) {
    bf16x8 kf[4];
#pragma unroll
    for (int d = 0; d < 4; ++d) {
      int col = (d * 16 + hi * 8) ^ ((ql & 7) * 8);
      kf[d] = *(const bf16x8*)&Ks[cur][(sl * 32 + ql) * 64 + col];
    }
    const unsigned short* vs = &Vs[cur][sl * 2048];
    bf16x8 v00 = *(const bf16x8*)&vs[ql * 16 + hi * 8];
    bf16x8 v01 = *(const bf16x8*)&vs[1024 + ql * 16 + hi * 8];
    bf16x8 v10 = *(const bf16x8*)&vs[512 + ql * 16 + hi * 8];
    bf16x8 v11 = *(const bf16x8*)&vs[1536 + ql * 16 + hi * 8];

    f32x16 s_;
#pragma unroll
    for (int r = 0; r < 16; ++r) s_[r] = 0.f;
#pragma unroll
    for (int d = 0; d < 4; ++d)
      s_ = __builtin_amdgcn_mfma_f32_32x32x16_bf16(kf[d], qf[d], s_, 0, 0, 0);
    if (sg == c) {
#pragma unroll
      for (int r = 0; r < 16; ++r) {
        int krow = (r & 3) + 8 * (r >> 2) + 4 * hi;
        s_[r] = (krow <= ql) ? s_[r] : -1e30f;
      }
    }
    float p[16];
#pragma unroll
    for (int r = 0; r < 16; ++r) { p[r] = exp2f(s_[r]); lsum += p[r]; }
    unsigned int wpk[8];
#pragma unroll
    for (int i = 0; i < 8; ++i)
      asm("v_cvt_pk_bf16_f32 %0, %1, %2" : "=v"(wpk[i]) : "v"(p[2 * i]), "v"(p[2 * i + 1]));
    asm volatile("v_permlane32_swap_b32 %0, %1" : "+v"(wpk[0]), "+v"(wpk[2]));
    asm volatile("v_permlane32_swap_b32 %0, %1" : "+v"(wpk[1]), "+v"(wpk[3]));
    asm volatile("v_permlane32_swap_b32 %0, %1" : "+v"(wpk[4]), "+v"(wpk[6]));
    asm volatile("v_permlane32_swap_b32 %0, %1" : "+v"(wpk[5]), "+v"(wpk[7]));
    union { unsigned int u[4]; bf16x8 v; } f0, f1;
    f0.u[0] = wpk[0]; f0.u[1] = wpk[1]; f0.u[2] = wpk[2]; f0.u[3] = wpk[3];
    f1.u[0] = wpk[4]; f1.u[1] = wpk[5]; f1.u[2] = wpk[6]; f1.u[3] = wpk[7];
    o0 = __builtin_amdgcn_mfma_f32_32x32x16_bf16(f0.v, v00, o0, 0, 0, 0);
    o1 = __builtin_amdgcn_mfma_f32_32x32x16_bf16(f0.v, v10, o1, 0, 0, 0);
    o0 = __builtin_amdgcn_mfma_f32_32x32x16_bf16(f1.v, v01, o0, 0, 0, 0);
    o1 = __builtin_amdgcn_mfma_f32_32x32x16_bf16(f1.v, v11, o1, 0, 0, 0);
  };

  stage(0, 0);
  for (int kt = 0; kt <= ktmax; ++kt) {
    const int cur = kt & 1;
    if (kt < ktmax) {
      stage(cur ^ 1, kt + 1);
      asm volatile("s_waitcnt vmcnt(4)" ::: "memory");
    } else {
      asm volatile("s_waitcnt vmcnt(0)" ::: "memory");
    }
    __builtin_amdgcn_sched_barrier(0);
    __builtin_amdgcn_s_barrier();
    __builtin_amdgcn_sched_barrier(0);
    const int s0 = kt * 2;
    if (s0 <= c) subtile(cur, 0, s0);
    if (s0 + 1 <= c) subtile(cur, 1, s0 + 1);
    __builtin_amdgcn_sched_barrier(0);
    __builtin_amdgcn_s_barrier();
    __builtin_amdgcn_sched_barrier(0);
  }

  // epilogue: per-wave, no cross-wave combine
  lsum += __shfl_xor(lsum, 32);
  float linv = 1.0f / lsum;
#pragma unroll
  for (int r = 0; r < 16; ++r) {
    int qr = (r & 3) + 8 * (r >> 2) + 4 * hi;
    float li = __shfl(linv, qr);
    unsigned short* zp = Z + ((long)(b * 2048 + q0 + qr) * 768 + hd * 64 + ql);
    zp[0]  = f2bf(o0[r] * li);
    zp[32] = f2bf(o1[r] * li);
  }
}

extern "C" void kernel_launch(void* const* d_in, const int* in_sizes, int n_in,
                              void* d_out, int out_size, void* d_ws, size_t ws_size,
                              hipStream_t stream) {
  const float* x  = (const float*)d_in[0];
  const float* wk = (const float*)d_in[1];
  const float* wq = (const float*)d_in[2];
  const float* wv = (const float*)d_in[3];
  const float* wo = (const float*)d_in[4];

  unsigned short* ws = (unsigned short*)d_ws;
  unsigned short* x_bf  = ws;                    // 3145728
  unsigned short* wk_bf = x_bf + 3145728;        // 589824 each, [Wk;Wq;Wv] contiguous
  unsigned short* wo_bf = wk_bf + 3 * 589824;
  unsigned short* qb    = wo_bf + 589824;        // 3145728 each
  unsigned short* kb    = qb + 3145728;
  unsigned short* v4b   = kb + 3145728;
  unsigned short* zb    = v4b + 3145728;

  cvt_all<<<5376, 256, 0, stream>>>(x, wk, wq, wv, wo, x_bf);
  gemm_qkv<<<dim3(18, 32), 256, 0, stream>>>(x_bf, wk_bf, kb, qb, v4b);
  attn<<<384, 256, 0, stream>>>(qb, kb, v4b, zb);
  gemm_out<<<dim3(6, 32), 256, 0, stream>>>(zb, wo_bf, (float*)d_out);
}

// Round 7
// 97.985 us; speedup vs baseline: 1.1684x; 1.1684x over previous
//
#include <hip/hip_runtime.h>
#include <hip/hip_bf16.h>

typedef __attribute__((ext_vector_type(8))) short bf16x8;
typedef __attribute__((ext_vector_type(4))) float f32x4;
typedef __attribute__((ext_vector_type(16))) float f32x16;

static __device__ __forceinline__ unsigned short f2bf(float f) {
  union { float f; unsigned int u; } v; v.f = f;
  unsigned int u = v.u;
  return (unsigned short)((u + 0x7FFFu + ((u >> 16) & 1u)) >> 16);
}

__device__ __forceinline__ void async_ld16(const void* g, void* l) {
  __builtin_amdgcn_global_load_lds(
      (const __attribute__((address_space(1))) unsigned int*)g,
      (__attribute__((address_space(3))) unsigned int*)l, 16, 0, 0);
}

// fp32 -> bf16 for x + W_K/W_Q/W_V/W_O; W_Q gets 0.125*log2(e) folded in
__global__ __launch_bounds__(256) void cvt_all(
    const float* __restrict__ x, const float* __restrict__ wk,
    const float* __restrict__ wq, const float* __restrict__ wv,
    const float* __restrict__ wo, unsigned short* __restrict__ dst) {
  int i = blockIdx.x * 256 + threadIdx.x;
  int e0 = i * 4;
  const float* src;
  int off;
  float scale = 1.0f;
  if (e0 < 3145728) { src = x; off = e0; }
  else {
    int j = e0 - 3145728;
    int a = j / 589824;
    off = j - a * 589824;
    src = (a == 0) ? wk : (a == 1) ? wq : (a == 2) ? wv : wo;
    if (a == 1) scale = 0.18033688011112042f;  // 0.125 * log2(e)
  }
  float4 v = *(const float4*)(src + off);
  ushort4 r;
  r.x = f2bf(v.x * scale); r.y = f2bf(v.y * scale);
  r.z = f2bf(v.z * scale); r.w = f2bf(v.w * scale);
  *(ushort4*)(dst + e0) = r;
}

// single-buffered 128x128 tile GEMM (m97 structure), K=768.
// MODE 0: fused QKV epilogue (N=2304 -> K4 tiled / qb [B,H,P,64] / V4 tiled)
// MODE 1: fp32 linear out (N=768)
template <int MODE>
__device__ __forceinline__ void gemm_body(
    const unsigned short* __restrict__ A,
    const unsigned short* __restrict__ Bt,
    void* __restrict__ outK, void* __restrict__ outQ, void* __restrict__ outV,
    unsigned short* As, unsigned short* Bs) {
  const int tid = threadIdx.x;
  const int w = tid >> 6;
  const int l = tid & 63;
  const int g = l >> 4;
  const int c = l & 15;
  const int m0 = blockIdx.y * 128;
  const int n0 = blockIdx.x * 128;
  const int wr = w >> 1, wc = w & 1;

  f32x4 acc[4][4];
#pragma unroll
  for (int i = 0; i < 4; i++)
#pragma unroll
    for (int j = 0; j < 4; j++) acc[i][j] = (f32x4){0.f, 0.f, 0.f, 0.f};

  const int lrow = l >> 3;
  const int lcolx = ((l & 7) ^ lrow) * 8;

  for (int kt = 0; kt < 12; ++kt) {
    const int k0 = kt * 64;
#pragma unroll
    for (int cc = 0; cc < 4; ++cc) {
      int chunk = cc * 4 + w;
      int row = chunk * 8 + lrow;
      async_ld16(A + (m0 + row) * 768 + k0 + lcolx, &As[chunk * 512]);
      async_ld16(Bt + (n0 + row) * 768 + k0 + lcolx, &Bs[chunk * 512]);
    }
    __syncthreads();
#pragma unroll
    for (int ks = 0; ks < 2; ++ks) {
      bf16x8 a[4], b[4];
#pragma unroll
      for (int mi = 0; mi < 4; ++mi) {
        int row = wr * 64 + mi * 16 + c;
        int col = (ks * 32 + g * 8) ^ ((row & 7) * 8);
        a[mi] = *(const bf16x8*)&As[row * 64 + col];
      }
#pragma unroll
      for (int ni = 0; ni < 4; ++ni) {
        int row = wc * 64 + ni * 16 + c;
        int col = (ks * 32 + g * 8) ^ ((row & 7) * 8);
        b[ni] = *(const bf16x8*)&Bs[row * 64 + col];
      }
#pragma unroll
      for (int mi = 0; mi < 4; ++mi)
#pragma unroll
        for (int ni = 0; ni < 4; ++ni)
          acc[mi][ni] = __builtin_amdgcn_mfma_f32_16x16x32_bf16(a[mi], b[ni], acc[mi][ni], 0, 0, 0);
    }
    __syncthreads();
  }

  if (MODE == 1) {
    float* O = (float*)outK;
#pragma unroll
    for (int mi = 0; mi < 4; ++mi)
#pragma unroll
      for (int ni = 0; ni < 4; ++ni)
#pragma unroll
        for (int r = 0; r < 4; ++r) {
          int m = m0 + wr * 64 + mi * 16 + g * 4 + r;
          int n = n0 + wc * 64 + ni * 16 + c;
          O[(long)m * 768 + n] = acc[mi][ni][r];
        }
  } else {
    const int which = (n0 >= 1536) ? 2 : (n0 >= 768 ? 1 : 0);
    const int nb = n0 - which * 768;
#pragma unroll
    for (int mi = 0; mi < 4; ++mi)
#pragma unroll
      for (int ni = 0; ni < 4; ++ni)
#pragma unroll
        for (int r = 0; r < 4; ++r) {
          int m = m0 + wr * 64 + mi * 16 + g * 4 + r;
          int nn = nb + wc * 64 + ni * 16 + c;
          int b = m >> 11, p = m & 2047;
          int h = nn >> 6, e = nn & 63;
          unsigned short val = f2bf(acc[mi][ni][r]);
          long bh = b * 12 + h;
          if (which == 0) {
            // K4 tiled: [bh][p/32][d/16][p&31][d&15]
            long idx = bh * 131072 + (p >> 5) * 2048 + (e >> 4) * 512 + (p & 31) * 16 + (e & 15);
            ((unsigned short*)outK)[idx] = val;
          } else if (which == 1) {
            ((unsigned short*)outQ)[((bh * 2048 + p) << 6) + e] = val;
          } else {
            // V4 tiled: [bh][p/16][e][p&15]
            long idx = bh * 131072 + (p >> 4) * 1024 + e * 16 + (p & 15);
            ((unsigned short*)outV)[idx] = val;
          }
        }
  }
}

__global__ __launch_bounds__(256) void gemm_qkv(
    const unsigned short* __restrict__ A,
    const unsigned short* __restrict__ Wkqv,   // [2304][768] = [Wk;Wq;Wv]
    unsigned short* __restrict__ k4b, unsigned short* __restrict__ qb,
    unsigned short* __restrict__ v4b) {
  __shared__ __align__(16) unsigned short As[8192];
  __shared__ __align__(16) unsigned short Bs[8192];
  gemm_body<0>(A, Wkqv, k4b, qb, v4b, As, Bs);
}

__global__ __launch_bounds__(256) void gemm_out(
    const unsigned short* __restrict__ A,
    const unsigned short* __restrict__ Bt,
    float* __restrict__ out) {
  __shared__ __align__(16) unsigned short As[8192];
  __shared__ __align__(16) unsigned short Bs[8192];
  gemm_body<1>(A, Bt, out, nullptr, nullptr, As, Bs);
}

// causal flash attention: swapped QK^T (32x32x16), in-register softmax,
// split-k x4: block = 4 waves on ONE 32-row q-chunk; LPT dispatch.
// K4/V4 tiled layouts -> every fragment load is a dense 1KB wave-read.
__global__ __launch_bounds__(256) void attn(
    const unsigned short* __restrict__ Q,
    const unsigned short* __restrict__ K4,
    const unsigned short* __restrict__ V4,
    unsigned short* __restrict__ Z) {
  __shared__ float2 Opart[3][16][64];
  __shared__ float Lpart[3][32];
  __shared__ float Linv[32];
  const int bx = blockIdx.x;                   // 0..1535
  const int cidx = bx / 24;                    // 0..63
  const int bh = bx - cidx * 24;               // 0..23
  const int c = 63 - cidx;                     // LPT: big chunks dispatched first
  const int tid = threadIdx.x;
  const int w = tid >> 6;                      // kpar 0..3
  const int l = tid & 63;
  const int ql = l & 31;
  const int hi = l >> 5;
  const int b = bh / 12, hd = bh - b * 12;
  const long base = (long)bh * 2048 * 64;
  const int q0 = c * 32;

  bf16x8 qf[4];
  {
    const unsigned short* qp = Q + base + (long)(q0 + ql) * 64 + hi * 8;
#pragma unroll
    for (int d = 0; d < 4; ++d) qf[d] = *(const bf16x8*)(qp + d * 16);
  }

  f32x16 o0, o1;
#pragma unroll
  for (int r = 0; r < 16; ++r) { o0[r] = 0.f; o1[r] = 0.f; }
  float lsum = 0.f;

  const unsigned short* kp = K4 + (long)bh * 131072 + ql * 16 + hi * 8;
  const unsigned short* vp = V4 + (long)bh * 131072 + ql * 16 + hi * 8;

  auto loadsub = [&](bf16x8* kf, bf16x8* v0, bf16x8* v1, int s) {
    const unsigned short* kps = kp + (long)s * 2048;
#pragma unroll
    for (int d = 0; d < 4; ++d) kf[d] = *(const bf16x8*)(kps + d * 512);
    const unsigned short* vps = vp + (long)s * 2048;
    v0[0] = *(const bf16x8*)(vps);
    v0[1] = *(const bf16x8*)(vps + 1024);
    v1[0] = *(const bf16x8*)(vps + 512);
    v1[1] = *(const bf16x8*)(vps + 1536);
  };

  auto compute = [&](const bf16x8* kf, const bf16x8* v0, const bf16x8* v1, bool diag) {
    __builtin_amdgcn_s_setprio(1);
    f32x16 s_;
#pragma unroll
    for (int r = 0; r < 16; ++r) s_[r] = 0.f;
#pragma unroll
    for (int d = 0; d < 4; ++d)
      s_ = __builtin_amdgcn_mfma_f32_32x32x16_bf16(kf[d], qf[d], s_, 0, 0, 0);
    __builtin_amdgcn_s_setprio(0);
    if (diag) {
#pragma unroll
      for (int r = 0; r < 16; ++r) {
        int krow = (r & 3) + 8 * (r >> 2) + 4 * hi;
        s_[r] = (krow <= ql) ? s_[r] : -1e30f;
      }
    }
    float p[16];
#pragma unroll
    for (int r = 0; r < 16; ++r) { p[r] = exp2f(s_[r]); lsum += p[r]; }
    unsigned int wpk[8];
#pragma unroll
    for (int i = 0; i < 8; ++i)
      asm("v_cvt_pk_bf16_f32 %0, %1, %2" : "=v"(wpk[i]) : "v"(p[2 * i]), "v"(p[2 * i + 1]));
    asm volatile("v_permlane32_swap_b32 %0, %1" : "+v"(wpk[0]), "+v"(wpk[2]));
    asm volatile("v_permlane32_swap_b32 %0, %1" : "+v"(wpk[1]), "+v"(wpk[3]));
    asm volatile("v_permlane32_swap_b32 %0, %1" : "+v"(wpk[4]), "+v"(wpk[6]));
    asm volatile("v_permlane32_swap_b32 %0, %1" : "+v"(wpk[5]), "+v"(wpk[7]));
    union { unsigned int u[4]; bf16x8 v; } f0, f1;
    f0.u[0] = wpk[0]; f0.u[1] = wpk[1]; f0.u[2] = wpk[2]; f0.u[3] = wpk[3];
    f1.u[0] = wpk[4]; f1.u[1] = wpk[5]; f1.u[2] = wpk[6]; f1.u[3] = wpk[7];
    __builtin_amdgcn_s_setprio(1);
    o0 = __builtin_amdgcn_mfma_f32_32x32x16_bf16(f0.v, v0[0], o0, 0, 0, 0);
    o1 = __builtin_amdgcn_mfma_f32_32x32x16_bf16(f0.v, v1[0], o1, 0, 0, 0);
    o0 = __builtin_amdgcn_mfma_f32_32x32x16_bf16(f1.v, v0[1], o0, 0, 0, 0);
    o1 = __builtin_amdgcn_mfma_f32_32x32x16_bf16(f1.v, v1[1], o1, 0, 0, 0);
    __builtin_amdgcn_s_setprio(0);
  };

  int s = w;
  if (s <= c) {
    bf16x8 kfA[4], vA0[2], vA1[2], kfB[4], vB0[2], vB1[2];
    loadsub(kfA, vA0, vA1, s);
    while (s + 8 <= c) {
      loadsub(kfB, vB0, vB1, s + 4);
      compute(kfA, vA0, vA1, false);
      loadsub(kfA, vA0, vA1, s + 8);
      compute(kfB, vB0, vB1, false);
      s += 8;
    }
    if (s + 4 <= c) {
      loadsub(kfB, vB0, vB1, s + 4);
      compute(kfA, vA0, vA1, false);
      compute(kfB, vB0, vB1, (s + 4) == c);
    } else {
      compute(kfA, vA0, vA1, s == c);
    }
  }

  lsum += __shfl_xor(lsum, 32);

  if (w) {
#pragma unroll
    for (int r = 0; r < 16; ++r) Opart[w - 1][r][l] = make_float2(o0[r], o1[r]);
    if (l < 32) Lpart[w - 1][l] = lsum;
  }
  __syncthreads();
  if (w == 0) {
    float ltot = lsum + Lpart[0][ql] + Lpart[1][ql] + Lpart[2][ql];
    if (l < 32) Linv[l] = 1.0f / ltot;
#pragma unroll
    for (int r = 0; r < 16; ++r) {
      float2 t0 = Opart[0][r][l], t1 = Opart[1][r][l], t2 = Opart[2][r][l];
      o0[r] += t0.x + t1.x + t2.x;
      o1[r] += t0.y + t1.y + t2.y;
    }
#pragma unroll
    for (int r = 0; r < 16; ++r) {
      int qr = (r & 3) + 8 * (r >> 2) + 4 * hi;
      float li = Linv[qr];
      unsigned short* zp = Z + ((long)(b * 2048 + q0 + qr) * 768 + hd * 64 + ql);
      zp[0]  = f2bf(o0[r] * li);
      zp[32] = f2bf(o1[r] * li);
    }
  }
}

extern "C" void kernel_launch(void* const* d_in, const int* in_sizes, int n_in,
                              void* d_out, int out_size, void* d_ws, size_t ws_size,
                              hipStream_t stream) {
  const float* x  = (const float*)d_in[0];
  const float* wk = (const float*)d_in[1];
  const float* wq = (const float*)d_in[2];
  const float* wv = (const float*)d_in[3];
  const float* wo = (const float*)d_in[4];

  unsigned short* ws = (unsigned short*)d_ws;
  unsigned short* x_bf  = ws;                    // 3145728
  unsigned short* wk_bf = x_bf + 3145728;        // 589824 each, [Wk;Wq;Wv] contiguous
  unsigned short* wo_bf = wk_bf + 3 * 589824;
  unsigned short* qb    = wo_bf + 589824;        // 3145728 each
  unsigned short* k4b   = qb + 3145728;
  unsigned short* v4b   = k4b + 3145728;
  unsigned short* zb    = v4b + 3145728;

  cvt_all<<<5376, 256, 0, stream>>>(x, wk, wq, wv, wo, x_bf);
  gemm_qkv<<<dim3(18, 32), 256, 0, stream>>>(x_bf, wk_bf, k4b, qb, v4b);
  attn<<<1536, 256, 0, stream>>>(qb, k4b, v4b, zb);
  gemm_out<<<dim3(6, 32), 256, 0, stream>>>(zb, wo_bf, (float*)d_out);
}